// Round 3
// baseline (602.033 us; speedup 1.0000x reference)
//
#include <hip/hip_runtime.h>

// Problem constants (from reference):
//   bpe_features [B, LAYERS, L, D] fp32
//   layer_w      [LAYERS]          fp32
//   word_ids     [B, L]            int32 (word j covers tokens 2j, 2j+1)
//   out          [B, MAX_WORDS, D] fp32
#define BB 16
#define LAYERS 13
#define LL 512
#define DD 1024
#define WW 256        // MAX_WORDS
#define D4 (DD/4)     // 256 f32x4 slots per row

typedef float f32x4 __attribute__((ext_vector_type(4)));

// ---------------------------------------------------------------------------
// THEORY (round 3): both prior kernels (4096x8KB blocks, 1024x32KB blocks)
// sit at 0.8-1.7 TB/s while the harness's own fillBuffer hits 6.5 TB/s in the
// same trace. VALU ~4%, coalescing perfect, MLP ample -> the remaining
// pattern-dependent limiter is DRAM row-buffer locality: ~3k concurrent
// 2MB-strided read streams thrash row activates. Fix: two LINEAR sweeps.
//   Phase 1: block order == ascending input addresses (b,l,word-group).
//            Applies softmax weight + membership mask, writes partial
//            [b][j][l][d] (218 MB into workspace; input loads nontemporal so
//            partials can stay resident in 256MB L3).
//   Phase 2: linear sweep of partial (208 KB contiguous per block), sum 13
//            layers, scale by 1/cnt, nt-store out.
// Fallback: if ws_size < 218 MB, launch the previous single-phase kernel.
// ---------------------------------------------------------------------------

#define JP 4          // words per block (both phases)
#define GPB (WW/JP)   // 64 word-groups per batch

__device__ __forceinline__ float softmax_invs(const float* __restrict__ layer_w,
                                              float* w) {
    float m = -3.402823e38f;
#pragma unroll
    for (int l = 0; l < LAYERS; ++l) {
        w[l] = layer_w[l];
        m = fmaxf(m, w[l]);
    }
    float s = 0.f;
#pragma unroll
    for (int l = 0; l < LAYERS; ++l) {
        w[l] = __expf(w[l] - m);
        s += w[l];
    }
    return 1.f / s;
}

// grid: BB*LAYERS*GPB blocks, 256 threads. blk = (b*13 + l)*64 + jg
// => consecutive blocks read consecutive 32 KB input spans: perfect sweep.
__global__ __launch_bounds__(256) void MorphologicalTagger_13657996001460_phase1(
    const float* __restrict__ bpe,       // [BB, LAYERS, LL, DD]
    const float* __restrict__ layer_w,   // [LAYERS]
    const int*   __restrict__ word_ids,  // [BB, LL]
    float*       __restrict__ partial)   // [BB, WW, LAYERS, DD]
{
    const int blk = blockIdx.x;
    const int jg  = blk & (GPB - 1);
    const int bl  = blk >> 6;
    const int l   = bl % LAYERS;
    const int b   = bl / LAYERS;
    const int j0  = jg * JP;
    const int t0  = 2 * j0;
    const int tid = threadIdx.x;

    float w[LAYERS];
    const float invs = softmax_invs(layer_w, w);
    const float wl = invs * w[l];

    // membership masks for the 8 tokens
    float sc[2 * JP];
#pragma unroll
    for (int k = 0; k < 2 * JP; ++k) {
        const int j = j0 + (k >> 1);
        sc[k] = (word_ids[b * LL + t0 + k] == j) ? wl : 0.f;
    }

    const f32x4* in =
        (const f32x4*)bpe + ((size_t)(b * LAYERS + l) * LL + (size_t)t0) * D4 + tid;
    f32x4* po = (f32x4*)partial +
        ((size_t)(b * WW + j0) * LAYERS + (size_t)l) * D4 + tid;

#pragma unroll
    for (int v = 0; v < JP; ++v) {
        // single-use input: nontemporal, don't displace L3 (partials live there)
        f32x4 x0 = __builtin_nontemporal_load(in + (size_t)(2 * v) * D4);
        f32x4 x1 = __builtin_nontemporal_load(in + (size_t)(2 * v + 1) * D4);
        f32x4 p  = sc[2 * v] * x0 + sc[2 * v + 1] * x1;
        // regular (cacheable) store: we WANT these resident for phase 2
        po[(size_t)v * LAYERS * D4] = p;
    }
}

// grid: BB*GPB blocks, 256 threads. Each block reads 208 KB contiguous.
__global__ __launch_bounds__(256) void MorphologicalTagger_13657996001460_phase2(
    const float* __restrict__ partial,   // [BB, WW, LAYERS, DD]
    const int*   __restrict__ word_ids,  // [BB, LL]
    float*       __restrict__ out)       // [BB, WW, DD]
{
    const int blk = blockIdx.x;
    const int b   = blk >> 6;
    const int jg  = blk & (GPB - 1);
    const int j0  = jg * JP;
    const int tid = threadIdx.x;

#pragma unroll
    for (int v = 0; v < JP; ++v) {
        const int j = j0 + v;
        const bool i0 = (word_ids[b * LL + 2 * j]     == j);
        const bool i1 = (word_ids[b * LL + 2 * j + 1] == j);
        const float cnt = (i0 ? 1.f : 0.f) + (i1 ? 1.f : 0.f);
        const float r   = 1.f / fmaxf(cnt, 1.f);

        const f32x4* pp = (const f32x4*)partial +
            ((size_t)(b * WW + j) * LAYERS) * D4 + tid;
        f32x4 acc = (f32x4)0.f;
#pragma unroll
        for (int l = 0; l < LAYERS; ++l)
            acc += pp[(size_t)l * D4];

        f32x4* op = (f32x4*)out + ((size_t)(b * WW + j)) * D4 + tid;
        __builtin_nontemporal_store(acc * r, op);
    }
}

// ---------------------------------------------------------------------------
// Fallback: previous verified single-phase kernel (used if ws too small).
// ---------------------------------------------------------------------------
__global__ __launch_bounds__(256) void MorphologicalTagger_13657996001460_kernel(
    const float* __restrict__ bpe,
    const float* __restrict__ layer_w,
    const int*   __restrict__ word_ids,
    float*       __restrict__ out)
{
    const int blk = blockIdx.x;
    const int b   = blk >> 6;
    const int jg  = blk & (GPB - 1);
    const int j0  = jg * JP;
    const int tid = threadIdx.x;

    float w[LAYERS];
    const float invs = softmax_invs(layer_w, w);

    const int t0 = 2 * j0;
    float sc[2 * JP];
#pragma unroll
    for (int k = 0; k < 2 * JP; ++k) {
        const int j = j0 + (k >> 1);
        sc[k] = (word_ids[b * LL + t0 + k] == j) ? 1.f : 0.f;
    }

    const f32x4* base =
        (const f32x4*)bpe + ((size_t)(b * LAYERS) * LL + (size_t)t0) * D4 + tid;
    const size_t lstride = (size_t)LL * D4;

    f32x4 acc[2 * JP];
#pragma unroll
    for (int k = 0; k < 2 * JP; ++k) acc[k] = (f32x4)0.f;

#pragma unroll
    for (int l = 0; l < LAYERS; ++l) {
        const f32x4* pl = base + (size_t)l * lstride;
#pragma unroll
        for (int k = 0; k < 2 * JP; ++k)
            acc[k] += w[l] * pl[(size_t)k * D4];
    }

#pragma unroll
    for (int v = 0; v < JP; ++v) {
        const float c = sc[2*v] + sc[2*v+1];
        const float r = invs / fmaxf(c, 1.f);
        f32x4 res = (sc[2*v] * r) * acc[2*v] + (sc[2*v+1] * r) * acc[2*v+1];
        f32x4* op = (f32x4*)out + ((size_t)b * WW + (size_t)(j0 + v)) * D4 + tid;
        __builtin_nontemporal_store(res, op);
    }
}

extern "C" void kernel_launch(void* const* d_in, const int* in_sizes, int n_in,
                              void* d_out, int out_size, void* d_ws, size_t ws_size,
                              hipStream_t stream) {
    const float* bpe      = (const float*)d_in[0];  // [16,13,512,1024]
    const float* layer_w  = (const float*)d_in[1];  // [13]
    const int*   word_ids = (const int*)d_in[2];    // [16,512]
    float* out = (float*)d_out;                     // [16,256,1024]

    const size_t need = (size_t)BB * WW * LAYERS * DD * sizeof(float); // 218 MB

    if (d_ws != nullptr && ws_size >= need) {
        float* partial = (float*)d_ws;
        dim3 block(256);
        dim3 g1(BB * LAYERS * GPB);   // 13312 blocks, linear input sweep
        MorphologicalTagger_13657996001460_phase1<<<g1, block, 0, stream>>>(
            bpe, layer_w, word_ids, partial);
        dim3 g2(BB * GPB);            // 1024 blocks, linear partial sweep
        MorphologicalTagger_13657996001460_phase2<<<g2, block, 0, stream>>>(
            partial, word_ids, out);
    } else {
        dim3 grid(BB * GPB);
        dim3 block(256);
        MorphologicalTagger_13657996001460_kernel<<<grid, block, 0, stream>>>(
            bpe, layer_w, word_ids, out);
    }
}

// Round 6
// 531.405 us; speedup vs baseline: 1.1329x; 1.1329x over previous
//
#include <hip/hip_runtime.h>

// Problem constants (from reference):
//   bpe_features [B, LAYERS, L, D] fp32
//   layer_w      [LAYERS]          fp32
//   word_ids     [B, L]            int32 (word j covers tokens 2j, 2j+1)
//   out          [B, MAX_WORDS, D] fp32
#define BB 16
#define LAYERS 13
#define LL 512
#define DD 1024
#define WW 256   // MAX_WORDS

typedef float f32x4 __attribute__((ext_vector_type(4)));

// Best-verified kernel (531.7 us dur_us; ~73 us true dispatch per the
// round-3 marginal-BW analysis: +436 MB of two-phase workspace traffic cost
// +70.4 us => bytes move at ~6.2 TB/s, i.e. this kernel is at the HBM read
// roofline and the rest of dur_us is harness reset work).
//
// One block per (b, word). 256 threads, each owns one float4 slice of D.
// Branch-free inner loop: segment-membership scales (0/1) and the 1/count
// divisor factor OUT of the layer reduction:
//   out = rcnt * ( s0 * sum_l w_l * x[l, 2j] + s1 * sum_l w_l * x[l, 2j+1] )
// so the K-loop is 26 unconditional, independent float4 loads kept in flight
// together.
__global__ __launch_bounds__(256) void MorphologicalTagger_13657996001460_kernel(
    const float* __restrict__ bpe,       // [BB, LAYERS, LL, DD]
    const float* __restrict__ layer_w,   // [LAYERS]
    const int*   __restrict__ word_ids,  // [BB, LL]
    float*       __restrict__ out)       // [BB, WW, DD]
{
    const int blk = blockIdx.x;
    const int b   = blk >> 8;    // / WW
    const int j   = blk & 255;   // % WW
    const int tid = threadIdx.x; // 0..255, float4 index into D

    // --- softmax weights (unnormalized exp; 1/sum folded into final scale) ---
    float w[LAYERS];
    float m = -3.402823e38f;
#pragma unroll
    for (int l = 0; l < LAYERS; ++l) {
        w[l] = layer_w[l];
        m = fmaxf(m, w[l]);
    }
    float s = 0.f;
#pragma unroll
    for (int l = 0; l < LAYERS; ++l) {
        w[l] = __expf(w[l] - m);
        s += w[l];
    }
    const float invs = 1.f / s;

    // --- segment membership for word j (tokens 2j, 2j+1), folded to scales ---
    const int n0 = 2 * j;
    const bool in0 = (word_ids[b * LL + n0]     == j);
    const bool in1 = (word_ids[b * LL + n0 + 1] == j);
    const float cnt  = (in0 ? 1.f : 0.f) + (in1 ? 1.f : 0.f);
    const float rcnt = invs / fmaxf(cnt, 1.f);
    const float s0 = in0 ? rcnt : 0.f;
    const float s1 = in1 ? rcnt : 0.f;

    // --- branch-free weighted reduction over layers, both tokens ---
    const int D4 = DD / 4;
    const f32x4* p =
        (const f32x4*)bpe + ((size_t)(b * LAYERS) * LL + (size_t)n0) * D4 + tid;
    const size_t lstride = (size_t)LL * D4;  // float4 stride between layers

    f32x4 a0 = (f32x4)0.f;
    f32x4 a1 = (f32x4)0.f;
#pragma unroll
    for (int l = 0; l < LAYERS; ++l) {
        f32x4 x0 = __builtin_nontemporal_load(p + (size_t)l * lstride);
        f32x4 x1 = __builtin_nontemporal_load(p + (size_t)l * lstride + D4);
        a0 += w[l] * x0;
        a1 += w[l] * x1;
    }

    f32x4 r = s0 * a0 + s1 * a1;
    f32x4* op = (f32x4*)out + ((size_t)b * WW + j) * D4 + tid;
    __builtin_nontemporal_store(r, op);
}

extern "C" void kernel_launch(void* const* d_in, const int* in_sizes, int n_in,
                              void* d_out, int out_size, void* d_ws, size_t ws_size,
                              hipStream_t stream) {
    const float* bpe      = (const float*)d_in[0];  // [16,13,512,1024]
    const float* layer_w  = (const float*)d_in[1];  // [13]
    const int*   word_ids = (const int*)d_in[2];    // [16,512]
    float* out = (float*)d_out;                     // [16,256,1024]

    dim3 grid(BB * WW);   // 4096 blocks
    dim3 block(256);
    MorphologicalTagger_13657996001460_kernel<<<grid, block, 0, stream>>>(
        bpe, layer_w, word_ids, out);
}